// Round 1
// 700.097 us; speedup vs baseline: 1.0250x; 1.0250x over previous
//
#include <hip/hip_runtime.h>
#include <math.h>

#define DIM 64
#define NT 4
#define NR 8
// tmeta layout: [0..3]=tcnt  [4..7]=tbase  [8..11]=tfill  [12]=padded_total

typedef __attribute__((ext_vector_type(8))) short bf16x8;   // 8 bf16 (4 VGPRs)
typedef __attribute__((ext_vector_type(4))) float f32x4;    // 4 fp32 acc

// ---- bf16 helpers (bit-level; values finite/small) ----
__device__ __forceinline__ unsigned short f2bf(float f) {
    unsigned u = __float_as_uint(f);
    return (unsigned short)((u + 0x7FFF + ((u >> 16) & 1)) >> 16);  // RNE
}
__device__ __forceinline__ float bf2f(unsigned short u) {
    return __uint_as_float((unsigned)u << 16);
}
__device__ __forceinline__ float4 bf4_to_f4(ushort4 u) {
    float4 f;
    f.x = bf2f(u.x); f.y = bf2f(u.y); f.z = bf2f(u.z); f.w = bf2f(u.w);
    return f;
}
__device__ __forceinline__ bf16x8 ldb16(const unsigned short* p) {
    return *((const bf16x8*)p);
}

__global__ void init_cnt8(int* __restrict__ cnt, int* __restrict__ cnt2, int M) {
    int i = blockIdx.x * blockDim.x + threadIdx.x;
    if (i < M) { cnt[i] = 0; cnt2[i] = 0; }
}

__global__ void init_order(int* __restrict__ order, int* __restrict__ tm, int cap) {
    int i = blockIdx.x * blockDim.x + threadIdx.x;
    if (i < cap) order[i] = -1;
    if (i < 16) tm[i] = 0;
}

// ---- per-wave ballot histogram of node types ----
__global__ void type_count(const int* __restrict__ ntype, int* __restrict__ tm, int N) {
    int i = blockIdx.x * blockDim.x + threadIdx.x;
    int t = (i < N) ? ntype[i] : -1;
    int lane = threadIdx.x & 63;
    #pragma unroll
    for (int tt = 0; tt < NT; tt++) {
        unsigned long long m = __ballot(t == tt);
        int c = __popcll(m);
        if (c && lane == (__ffsll((long long)m) - 1)) atomicAdd(&tm[tt], c);
    }
}

__global__ void type_scan(int* __restrict__ tm) {
    if (threadIdx.x == 0 && blockIdx.x == 0) {
        int b = 0;
        for (int t = 0; t < NT; t++) { tm[4 + t] = b; b += ((tm[t] + 63) >> 6) << 6; }
        tm[12] = b;
    }
}

__global__ void type_scatter(const int* __restrict__ ntype, int* __restrict__ tm,
                             int* __restrict__ order, int N) {
    int i = blockIdx.x * blockDim.x + threadIdx.x;
    int t = (i < N) ? ntype[i] : -1;
    int lane = threadIdx.x & 63;
    #pragma unroll
    for (int tt = 0; tt < NT; tt++) {
        unsigned long long m = __ballot(t == tt);
        int c = __popcll(m);
        if (!c) continue;
        int ldr = __ffsll((long long)m) - 1;
        int base = 0;
        if (lane == ldr) base = atomicAdd(&tm[8 + tt], c);
        base = __shfl(base, ldr, 64);
        if (t == tt) {
            int rank = __popcll(m & ((1ull << lane) - 1ull));
            order[tm[4 + tt] + base + rank] = i;
        }
    }
}

// ---- typed K/Q/V projection: 64-node tile; all outputs bf16 ----
__global__ void proj_typed(const float* __restrict__ h, const int* __restrict__ ntype,
                           const int* __restrict__ order, const int* __restrict__ tm,
                           const float* __restrict__ Wk, const float* __restrict__ Wq,
                           const float* __restrict__ Wv,
                           unsigned short* __restrict__ kbf, unsigned short* __restrict__ qbf,
                           unsigned short* __restrict__ vbf, int N) {
    __shared__ float xs[64][68];
    __shared__ float wsm[64][64];
    int t  = threadIdx.x;
    int n0 = blockIdx.x * 64;
    if (n0 >= tm[12]) return;
    int first = order[n0];
    if (first < 0) return;
    int ty = ntype[first];

    #pragma unroll
    for (int i = 0; i < 4; i++) {
        int idx = t + 256 * i;
        int row = idx >> 4, c4 = idx & 15;
        int gn = order[n0 + row];
        float4 xv = make_float4(0.f, 0.f, 0.f, 0.f);
        if (gn >= 0) xv = ((const float4*)(h + (size_t)gn * DIM))[c4];
        ((float4*)&xs[row][0])[c4] = xv;
    }

    const float* Ws[3] = { Wk + (size_t)ty * DIM * DIM,
                           Wq + (size_t)ty * DIM * DIM,
                           Wv + (size_t)ty * DIM * DIM };
    unsigned short* Os[3] = { kbf, qbf, vbf };

    int og  = t & 15;
    int ng4 = (t >> 4) * 4;
    int g[4];
    #pragma unroll
    for (int j = 0; j < 4; j++) g[j] = order[n0 + ng4 + j];

    for (int mm = 0; mm < 3; mm++) {
        const float4* wg = (const float4*)Ws[mm];
        float4* wl = (float4*)&wsm[0][0];
        __syncthreads();
        #pragma unroll
        for (int i = 0; i < 4; i++) wl[t + 256 * i] = wg[t + 256 * i];
        __syncthreads();
        float4 a[4];
        #pragma unroll
        for (int j = 0; j < 4; j++) a[j] = make_float4(0.f, 0.f, 0.f, 0.f);
        #pragma unroll 8
        for (int d = 0; d < DIM; d++) {
            float4 wv = ((const float4*)&wsm[d][0])[og];
            #pragma unroll
            for (int j = 0; j < 4; j++) {
                float xx = xs[ng4 + j][d];
                a[j].x = fmaf(xx, wv.x, a[j].x); a[j].y = fmaf(xx, wv.y, a[j].y);
                a[j].z = fmaf(xx, wv.z, a[j].z); a[j].w = fmaf(xx, wv.w, a[j].w);
            }
        }
        unsigned short* ob = Os[mm];
        #pragma unroll
        for (int j = 0; j < 4; j++)
            if (g[j] >= 0)
                ((ushort4*)(ob + (size_t)g[j] * DIM))[og] =
                    make_ushort4(f2bf(a[j].x), f2bf(a[j].y), f2bf(a[j].z), f2bf(a[j].w));
    }
}

// ---- transpose + cast relation matrices: Wt[r][n][k] = bf16(W[r][k][n]) ----
__global__ void prep_w(const float* __restrict__ A, const float* __restrict__ Mw,
                       unsigned short* __restrict__ At, unsigned short* __restrict__ Mt) {
    int i = blockIdx.x * blockDim.x + threadIdx.x;
    if (i >= NR * DIM * DIM) return;
    int r = i >> 12;
    int idx = i & 4095;
    int n = idx >> 6;
    int k = idx & 63;
    At[i] = f2bf(A[(r << 12) + k * DIM + n]);
    Mt[i] = f2bf(Mw[(r << 12) + k * DIM + n]);
}

// ---------------- CSR build over (dst*8 + etype) buckets ----------------
__global__ void hist8(const int* __restrict__ dst, const int* __restrict__ et,
                      int* __restrict__ cnt, int E) {
    int e = blockIdx.x * blockDim.x + threadIdx.x;
    if (e < E) atomicAdd(&cnt[dst[e] * NR + et[e]], 1);
}

__global__ void scan1(const int* __restrict__ cnt, int* __restrict__ off,
                      int* __restrict__ bsum, int M) {
    __shared__ int buf[1024];
    int tid = threadIdx.x;
    int i = blockIdx.x * 1024 + tid;
    int x = (i < M) ? cnt[i] : 0;
    buf[tid] = x;
    __syncthreads();
    for (int s = 1; s < 1024; s <<= 1) {
        int t = (tid >= s) ? buf[tid - s] : 0;
        __syncthreads();
        buf[tid] += t;
        __syncthreads();
    }
    if (i < M) off[i] = buf[tid] - x;
    if (tid == 1023) bsum[blockIdx.x] = buf[1023];
}

__global__ void scan2(int* __restrict__ bsum, int nb) {
    __shared__ int buf[1024];
    __shared__ int carry;
    int tid = threadIdx.x;
    if (tid == 0) carry = 0;
    __syncthreads();
    for (int base = 0; base < nb; base += 1024) {
        int i = base + tid;
        int x = (i < nb) ? bsum[i] : 0;
        buf[tid] = x;
        __syncthreads();
        for (int s = 1; s < 1024; s <<= 1) {
            int t = (tid >= s) ? buf[tid - s] : 0;
            __syncthreads();
            buf[tid] += t;
            __syncthreads();
        }
        if (i < nb) bsum[i] = carry + buf[tid] - x;
        __syncthreads();
        if (tid == 1023) carry += buf[1023];
        __syncthreads();
    }
}

__global__ void scan3(int* __restrict__ off, const int* __restrict__ bsum, int M, int E) {
    int i = blockIdx.x * 1024 + threadIdx.x;
    if (i < M) off[i] += bsum[blockIdx.x];
    if (i == 0) off[M] = E;
}

__global__ void scatter8(const int* __restrict__ src, const int* __restrict__ dst,
                         const int* __restrict__ et, const int* __restrict__ off,
                         int* __restrict__ cnt2, int* __restrict__ se, int E) {
    int e = blockIdx.x * blockDim.x + threadIdx.x;
    if (e >= E) return;
    int key = dst[e] * NR + et[e];
    int p = off[key] + atomicAdd(&cnt2[key], 1);
    se[p] = src[e];
}

// =====================================================================
// Fused edge phase: one wave owns 16 dst nodes; zero block barriers.
// Per relation r:
//   qW tile  = q_frags @ A_r          (MFMA, frags straight from L2-hot At)
//   walk buckets (n, r): ex = exp(<qW[n], k[src]> * pri); D[n] += ex;
//                        P[n] += ex * v[src]      (single pass, no max-shift)
//   U += P @ M_r                      (MFMA, frags from L2-hot Mt)
// Epilogue: agg[n] = U[n] / D[n].
// C/D layout row = quad*4+reg is exactly the node set group 'quad' walked,
// so D never crosses lanes. LDS hand-offs are same-wave (DS in-order) with
// an lgkmcnt(0)+memory-clobber fence at each phase boundary.
// =====================================================================
__global__ void __launch_bounds__(256)
fused_edge(const unsigned short* __restrict__ qbf,
           const unsigned short* __restrict__ kbf,
           const unsigned short* __restrict__ vbf,
           const unsigned short* __restrict__ At,
           const unsigned short* __restrict__ Mt,
           const int* __restrict__ se, const int* __restrict__ off8,
           const float* __restrict__ rel_pri,
           float* __restrict__ agg, int N) {
    __shared__ __align__(16) float qw[4][16][68];           // per-wave qW tile (f32)
    __shared__ __align__(16) unsigned short pl[4][16][72];  // per-wave P tile (bf16)
    const int t    = threadIdx.x;
    const int wave = t >> 6;
    const int m    = t & 15;         // MFMA col / lane-in-group
    const int quad = (t >> 4) & 3;   // MFMA quad == walk group
    const int n0   = blockIdx.x * 64 + wave * 16;
    if (n0 >= N) return;

    // Q A-frags, held across all r: lane m+16q holds q[n0+m][kh*32 + q*8 + j]
    bf16x8 qa0 = {0,0,0,0,0,0,0,0}, qa1 = {0,0,0,0,0,0,0,0};
    {
        const int gn = n0 + m;
        if (gn < N) {
            const unsigned short* qp = qbf + ((size_t)gn << 6) + quad * 8;
            qa0 = *((const bf16x8*)qp);
            qa1 = *((const bf16x8*)(qp + 32));
        }
    }

    f32x4 u0 = {0.f,0.f,0.f,0.f}, u1 = u0, u2 = u0, u3 = u0;  // U accumulator
    float d0 = 0.f, d1 = 0.f, d2 = 0.f, d3 = 0.f;             // denominators

    for (int r = 0; r < NR; r++) {
        // ---- qW tile via MFMA ----
        const unsigned short* Ar = At + ((size_t)r << 12);
        f32x4 c0 = {0.f,0.f,0.f,0.f}, c1 = c0, c2 = c0, c3 = c0;
        c0 = __builtin_amdgcn_mfma_f32_16x16x32_bf16(qa0, ldb16(Ar + (( 0 + m) << 6)      + quad * 8), c0, 0, 0, 0);
        c1 = __builtin_amdgcn_mfma_f32_16x16x32_bf16(qa0, ldb16(Ar + ((16 + m) << 6)      + quad * 8), c1, 0, 0, 0);
        c2 = __builtin_amdgcn_mfma_f32_16x16x32_bf16(qa0, ldb16(Ar + ((32 + m) << 6)      + quad * 8), c2, 0, 0, 0);
        c3 = __builtin_amdgcn_mfma_f32_16x16x32_bf16(qa0, ldb16(Ar + ((48 + m) << 6)      + quad * 8), c3, 0, 0, 0);
        c0 = __builtin_amdgcn_mfma_f32_16x16x32_bf16(qa1, ldb16(Ar + (( 0 + m) << 6) + 32 + quad * 8), c0, 0, 0, 0);
        c1 = __builtin_amdgcn_mfma_f32_16x16x32_bf16(qa1, ldb16(Ar + ((16 + m) << 6) + 32 + quad * 8), c1, 0, 0, 0);
        c2 = __builtin_amdgcn_mfma_f32_16x16x32_bf16(qa1, ldb16(Ar + ((32 + m) << 6) + 32 + quad * 8), c2, 0, 0, 0);
        c3 = __builtin_amdgcn_mfma_f32_16x16x32_bf16(qa1, ldb16(Ar + ((48 + m) << 6) + 32 + quad * 8), c3, 0, 0, 0);

        // scatter D-layout (row=quad*4+reg, col=nb*16+m) to LDS
        #pragma unroll
        for (int reg = 0; reg < 4; reg++) {
            float* qr = &qw[wave][quad * 4 + reg][m];
            qr[ 0] = c0[reg]; qr[16] = c1[reg]; qr[32] = c2[reg]; qr[48] = c3[reg];
        }
        asm volatile("s_waitcnt lgkmcnt(0)" ::: "memory");

        // ---- single-pass walk: group 'quad' handles nodes quad*4 .. quad*4+3 ----
        const float pri = rel_pri[r] * 0.125f;
        #pragma unroll
        for (int j = 0; j < 4; j++) {
            const int n = n0 + quad * 4 + j;
            int i0 = 0, i1 = 0;
            if (n < N) {
                i0 = off8[n * NR + r];
                i1 = off8[n * NR + r + 1];
            }
            const float4 tv = *((const float4*)&qw[wave][quad * 4 + j][m * 4]);
            float4 pacc = make_float4(0.f, 0.f, 0.f, 0.f);
            float dd = 0.f;
            int i = i0;
            for (; i + 1 < i1; i += 2) {   // 2-way unroll: avg bucket size == 2
                const int s0 = se[i], s1 = se[i + 1];
                float4 kv0 = bf4_to_f4(((const ushort4*)(kbf + ((size_t)s0 << 6)))[m]);
                float4 kv1 = bf4_to_f4(((const ushort4*)(kbf + ((size_t)s1 << 6)))[m]);
                float4 vv0 = bf4_to_f4(((const ushort4*)(vbf + ((size_t)s0 << 6)))[m]);
                float4 vv1 = bf4_to_f4(((const ushort4*)(vbf + ((size_t)s1 << 6)))[m]);
                float p0 = kv0.x * tv.x + kv0.y * tv.y + kv0.z * tv.z + kv0.w * tv.w;
                float p1 = kv1.x * tv.x + kv1.y * tv.y + kv1.z * tv.z + kv1.w * tv.w;
                p0 += __shfl_xor(p0, 8, 16);  p1 += __shfl_xor(p1, 8, 16);
                p0 += __shfl_xor(p0, 4, 16);  p1 += __shfl_xor(p1, 4, 16);
                p0 += __shfl_xor(p0, 2, 16);  p1 += __shfl_xor(p1, 2, 16);
                p0 += __shfl_xor(p0, 1, 16);  p1 += __shfl_xor(p1, 1, 16);
                const float e0 = __expf(p0 * pri);
                const float e1 = __expf(p1 * pri);
                dd += e0 + e1;
                pacc.x = fmaf(e1, vv1.x, fmaf(e0, vv0.x, pacc.x));
                pacc.y = fmaf(e1, vv1.y, fmaf(e0, vv0.y, pacc.y));
                pacc.z = fmaf(e1, vv1.z, fmaf(e0, vv0.z, pacc.z));
                pacc.w = fmaf(e1, vv1.w, fmaf(e0, vv0.w, pacc.w));
            }
            if (i < i1) {
                const int s0 = se[i];
                float4 kv0 = bf4_to_f4(((const ushort4*)(kbf + ((size_t)s0 << 6)))[m]);
                float4 vv0 = bf4_to_f4(((const ushort4*)(vbf + ((size_t)s0 << 6)))[m]);
                float p0 = kv0.x * tv.x + kv0.y * tv.y + kv0.z * tv.z + kv0.w * tv.w;
                p0 += __shfl_xor(p0, 8, 16);
                p0 += __shfl_xor(p0, 4, 16);
                p0 += __shfl_xor(p0, 2, 16);
                p0 += __shfl_xor(p0, 1, 16);
                const float e0 = __expf(p0 * pri);
                dd += e0;
                pacc.x = fmaf(e0, vv0.x, pacc.x);
                pacc.y = fmaf(e0, vv0.y, pacc.y);
                pacc.z = fmaf(e0, vv0.z, pacc.z);
                pacc.w = fmaf(e0, vv0.w, pacc.w);
            }
            ((ushort4*)&pl[wave][quad * 4 + j][0])[m] =
                make_ushort4(f2bf(pacc.x), f2bf(pacc.y), f2bf(pacc.z), f2bf(pacc.w));
            if      (j == 0) d0 += dd;
            else if (j == 1) d1 += dd;
            else if (j == 2) d2 += dd;
            else             d3 += dd;
        }
        asm volatile("s_waitcnt lgkmcnt(0)" ::: "memory");

        // ---- U += P @ M_r ----
        const unsigned short* Mr = Mt + ((size_t)r << 12);
        const bf16x8 pa0 = *((const bf16x8*)&pl[wave][m][quad * 8]);
        const bf16x8 pa1 = *((const bf16x8*)&pl[wave][m][32 + quad * 8]);
        u0 = __builtin_amdgcn_mfma_f32_16x16x32_bf16(pa0, ldb16(Mr + (( 0 + m) << 6)      + quad * 8), u0, 0, 0, 0);
        u1 = __builtin_amdgcn_mfma_f32_16x16x32_bf16(pa0, ldb16(Mr + ((16 + m) << 6)      + quad * 8), u1, 0, 0, 0);
        u2 = __builtin_amdgcn_mfma_f32_16x16x32_bf16(pa0, ldb16(Mr + ((32 + m) << 6)      + quad * 8), u2, 0, 0, 0);
        u3 = __builtin_amdgcn_mfma_f32_16x16x32_bf16(pa0, ldb16(Mr + ((48 + m) << 6)      + quad * 8), u3, 0, 0, 0);
        u0 = __builtin_amdgcn_mfma_f32_16x16x32_bf16(pa1, ldb16(Mr + (( 0 + m) << 6) + 32 + quad * 8), u0, 0, 0, 0);
        u1 = __builtin_amdgcn_mfma_f32_16x16x32_bf16(pa1, ldb16(Mr + ((16 + m) << 6) + 32 + quad * 8), u1, 0, 0, 0);
        u2 = __builtin_amdgcn_mfma_f32_16x16x32_bf16(pa1, ldb16(Mr + ((32 + m) << 6) + 32 + quad * 8), u2, 0, 0, 0);
        u3 = __builtin_amdgcn_mfma_f32_16x16x32_bf16(pa1, ldb16(Mr + ((48 + m) << 6) + 32 + quad * 8), u3, 0, 0, 0);
        asm volatile("s_waitcnt lgkmcnt(0)" ::: "memory");
    }

    // ---- epilogue: agg[n] = U[n] / D[n]  (rows quad*4+reg == group's nodes) ----
    #pragma unroll
    for (int reg = 0; reg < 4; reg++) {
        const int n = n0 + quad * 4 + reg;
        if (n >= N) continue;
        const float dv  = (reg == 0) ? d0 : (reg == 1) ? d1 : (reg == 2) ? d2 : d3;
        const float inv = (dv == 0.f) ? 0.f : 1.f / dv;
        float* rowp = agg + ((size_t)n << 6) + m;
        rowp[ 0] = u0[reg] * inv;
        rowp[16] = u1[reg] * inv;
        rowp[32] = u2[reg] * inv;
        rowp[48] = u3[reg] * inv;
    }
}

// ------- typed output GEMM: 64-node tile, sigmoid(skip)*W staged in LDS -------
__global__ void out_typed(const float* __restrict__ agg, const int* __restrict__ ntype,
                          const int* __restrict__ order, const int* __restrict__ tm,
                          const float* __restrict__ Wa, const float* __restrict__ skip,
                          float* __restrict__ out, int N) {
    __shared__ float xs[64][68];
    __shared__ float wsm[64][64];
    int t  = threadIdx.x;
    int n0 = blockIdx.x * 64;
    if (n0 >= tm[12]) return;
    int first = order[n0];
    if (first < 0) return;
    int ty = ntype[first];
    float sg = 1.f / (1.f + expf(-skip[ty]));

    const float4* wg = (const float4*)(Wa + (size_t)ty * DIM * DIM);
    float4* wl = (float4*)&wsm[0][0];
    #pragma unroll
    for (int i = 0; i < 4; i++) {
        float4 w = wg[t + 256 * i];
        w.x *= sg; w.y *= sg; w.z *= sg; w.w *= sg;
        wl[t + 256 * i] = w;
    }
    #pragma unroll
    for (int i = 0; i < 4; i++) {
        int idx = t + 256 * i;
        int row = idx >> 4, c4 = idx & 15;
        int gn = order[n0 + row];
        float4 xv = make_float4(0.f, 0.f, 0.f, 0.f);
        if (gn >= 0) xv = ((const float4*)(agg + (size_t)gn * DIM))[c4];
        ((float4*)&xs[row][0])[c4] = xv;
    }
    __syncthreads();

    int og  = t & 15;
    int ng4 = (t >> 4) * 4;
    float4 a0 = make_float4(0.f,0.f,0.f,0.f), a1 = a0, a2 = a0, a3 = a0;
    #pragma unroll 8
    for (int d = 0; d < DIM; d++) {
        float4 wv = ((const float4*)&wsm[d][0])[og];
        float x0 = xs[ng4 + 0][d];
        float x1 = xs[ng4 + 1][d];
        float x2 = xs[ng4 + 2][d];
        float x3 = xs[ng4 + 3][d];
        a0.x = fmaf(x0, wv.x, a0.x); a0.y = fmaf(x0, wv.y, a0.y);
        a0.z = fmaf(x0, wv.z, a0.z); a0.w = fmaf(x0, wv.w, a0.w);
        a1.x = fmaf(x1, wv.x, a1.x); a1.y = fmaf(x1, wv.y, a1.y);
        a1.z = fmaf(x1, wv.z, a1.z); a1.w = fmaf(x1, wv.w, a1.w);
        a2.x = fmaf(x2, wv.x, a2.x); a2.y = fmaf(x2, wv.y, a2.y);
        a2.z = fmaf(x2, wv.z, a2.z); a2.w = fmaf(x2, wv.w, a2.w);
        a3.x = fmaf(x3, wv.x, a3.x); a3.y = fmaf(x3, wv.y, a3.y);
        a3.z = fmaf(x3, wv.z, a3.z); a3.w = fmaf(x3, wv.w, a3.w);
    }
    int g0 = order[n0 + ng4 + 0];
    int g1 = order[n0 + ng4 + 1];
    int g2 = order[n0 + ng4 + 2];
    int g3 = order[n0 + ng4 + 3];
    if (g0 >= 0) ((float4*)(out + (size_t)g0 * DIM))[og] = a0;
    if (g1 >= 0) ((float4*)(out + (size_t)g1 * DIM))[og] = a1;
    if (g2 >= 0) ((float4*)(out + (size_t)g2 * DIM))[og] = a2;
    if (g3 >= 0) ((float4*)(out + (size_t)g3 * DIM))[og] = a3;
}

extern "C" void kernel_launch(void* const* d_in, const int* in_sizes, int n_in,
                              void* d_out, int out_size, void* d_ws, size_t ws_size,
                              hipStream_t stream) {
    const float* h       = (const float*)d_in[0];
    const int*   ntype   = (const int*)  d_in[1];
    const int*   src     = (const int*)  d_in[2];
    const int*   dst     = (const int*)  d_in[3];
    const int*   et      = (const int*)  d_in[4];
    const float* k_lin   = (const float*)d_in[5];
    const float* q_lin   = (const float*)d_in[6];
    const float* v_lin   = (const float*)d_in[7];
    const float* a_lin   = (const float*)d_in[8];
    const float* rel_att = (const float*)d_in[9];
    const float* rel_msg = (const float*)d_in[10];
    const float* rel_pri = (const float*)d_in[11];
    const float* skip    = (const float*)d_in[12];

    int N = in_sizes[1];
    int E = in_sizes[2];
    int M = N * NR;
    int ocap = N + NT * 64;

    float* ws = (float*)d_ws;
    size_t o = 0;
    unsigned short* kbf = (unsigned short*)(ws + o); o += (size_t)N * DIM / 2;
    unsigned short* qbf = (unsigned short*)(ws + o); o += (size_t)N * DIM / 2;
    unsigned short* vbf = (unsigned short*)(ws + o); o += (size_t)N * DIM / 2;
    float* agg  = ws + o; o += (size_t)N * DIM;
    int* off8   = (int*)(ws + o); o += (size_t)M + 8;
    int* cnt8   = (int*)(ws + o); o += (size_t)M;
    int* cnt28  = (int*)(ws + o); o += (size_t)M;
    int* se     = (int*)(ws + o); o += (size_t)E;
    int* bsum   = (int*)(ws + o); o += 1024;
    int* order  = (int*)(ws + o); o += (size_t)ocap;
    int* tm     = (int*)(ws + o); o += 16;
    unsigned short* At = (unsigned short*)(ws + o); o += (size_t)NR * DIM * DIM / 2;
    unsigned short* Mt = (unsigned short*)(ws + o); o += (size_t)NR * DIM * DIM / 2;

    float* out = (float*)d_out;

    // ---- type sort ----
    init_order<<<(ocap + 255) / 256, 256, 0, stream>>>(order, tm, ocap);
    type_count<<<(N + 255) / 256, 256, 0, stream>>>(ntype, tm, N);
    type_scan<<<1, 64, 0, stream>>>(tm);
    type_scatter<<<(N + 255) / 256, 256, 0, stream>>>(ntype, tm, order, N);

    // ---- typed fused projections (k,q,v -> bf16) ----
    int gridT = (N + NT * 64 + 63) / 64;
    proj_typed<<<gridT, 256, 0, stream>>>(h, ntype, order, tm, k_lin, q_lin, v_lin,
                                          kbf, qbf, vbf, N);

    // ---- relation weight transpose+cast (for MFMA B-operand) ----
    prep_w<<<(NR * DIM * DIM + 255) / 256, 256, 0, stream>>>(rel_att, rel_msg, At, Mt);

    // ---- CSR build over (dst, etype) buckets ----
    init_cnt8<<<(M + 255) / 256, 256, 0, stream>>>(cnt8, cnt28, M);
    hist8<<<(E + 255) / 256, 256, 0, stream>>>(dst, et, cnt8, E);
    int nb = (M + 1023) / 1024;
    scan1<<<nb, 1024, 0, stream>>>(cnt8, off8, bsum, M);
    scan2<<<1, 1024, 0, stream>>>(bsum, nb);
    scan3<<<nb, 1024, 0, stream>>>(off8, bsum, M, E);
    scatter8<<<(E + 255) / 256, 256, 0, stream>>>(src, dst, et, off8, cnt28, se, E);

    // ---- fused edge phase: qW-MFMA + single-pass walk + P@M-MFMA ----
    int nb64 = (N + 63) / 64;
    fused_edge<<<nb64, 256, 0, stream>>>(qbf, kbf, vbf, At, Mt, se, off8,
                                         rel_pri, agg, N);

    // ---- typed output GEMM ----
    out_typed<<<gridT, 256, 0, stream>>>(agg, ntype, order, tm, a_lin, skip, out, N);
}

// Round 2
// 687.722 us; speedup vs baseline: 1.0434x; 1.0180x over previous
//
#include <hip/hip_runtime.h>
#include <math.h>

#define DIM 64
#define NT 4
#define NR 8
// tmeta layout: [0..3]=tcnt  [4..7]=tbase  [8..11]=tfill  [12]=padded_total

typedef __attribute__((ext_vector_type(8))) short bf16x8;   // 8 bf16 (4 VGPRs)
typedef __attribute__((ext_vector_type(8))) unsigned short u16x8;
typedef __attribute__((ext_vector_type(4))) float f32x4;    // 4 fp32 acc

// ---- bf16 helpers (bit-level; values finite/small) ----
__device__ __forceinline__ unsigned short f2bf(float f) {
    unsigned u = __float_as_uint(f);
    return (unsigned short)((u + 0x7FFF + ((u >> 16) & 1)) >> 16);  // RNE
}
__device__ __forceinline__ float bf2f(unsigned short u) {
    return __uint_as_float((unsigned)u << 16);
}
__device__ __forceinline__ bf16x8 ldb16(const unsigned short* p) {
    return *((const bf16x8*)p);
}

// ---- per-wave ballot histogram of node types ----
__global__ void type_count(const int* __restrict__ ntype, int* __restrict__ tm, int N) {
    int i = blockIdx.x * blockDim.x + threadIdx.x;
    int t = (i < N) ? ntype[i] : -1;
    int lane = threadIdx.x & 63;
    #pragma unroll
    for (int tt = 0; tt < NT; tt++) {
        unsigned long long m = __ballot(t == tt);
        int c = __popcll(m);
        if (c && lane == (__ffsll((long long)m) - 1)) atomicAdd(&tm[tt], c);
    }
}

__global__ void type_scan(int* __restrict__ tm) {
    if (threadIdx.x == 0 && blockIdx.x == 0) {
        int b = 0;
        for (int t = 0; t < NT; t++) { tm[4 + t] = b; b += ((tm[t] + 63) >> 6) << 6; }
        tm[12] = b;
    }
}

__global__ void type_scatter(const int* __restrict__ ntype, int* __restrict__ tm,
                             int* __restrict__ order, int N) {
    int i = blockIdx.x * blockDim.x + threadIdx.x;
    int t = (i < N) ? ntype[i] : -1;
    int lane = threadIdx.x & 63;
    #pragma unroll
    for (int tt = 0; tt < NT; tt++) {
        unsigned long long m = __ballot(t == tt);
        int c = __popcll(m);
        if (!c) continue;
        int ldr = __ffsll((long long)m) - 1;
        int base = 0;
        if (lane == ldr) base = atomicAdd(&tm[8 + tt], c);
        base = __shfl(base, ldr, 64);
        if (t == tt) {
            int rank = __popcll(m & ((1ull << lane) - 1ull));
            order[tm[4 + tt] + base + rank] = i;
        }
    }
}

// ---- typed K/Q/V projection: 64-node tile; k,v interleaved into kv[n][128] ----
__global__ void proj_typed(const float* __restrict__ h, const int* __restrict__ ntype,
                           const int* __restrict__ order, const int* __restrict__ tm,
                           const float* __restrict__ Wk, const float* __restrict__ Wq,
                           const float* __restrict__ Wv,
                           unsigned short* __restrict__ kvbf, unsigned short* __restrict__ qbf,
                           int N) {
    __shared__ float xs[64][68];
    __shared__ float wsm[64][64];
    int t  = threadIdx.x;
    int n0 = blockIdx.x * 64;
    if (n0 >= tm[12]) return;
    int first = order[n0];
    if (first < 0) return;
    int ty = ntype[first];

    #pragma unroll
    for (int i = 0; i < 4; i++) {
        int idx = t + 256 * i;
        int row = idx >> 4, c4 = idx & 15;
        int gn = order[n0 + row];
        float4 xv = make_float4(0.f, 0.f, 0.f, 0.f);
        if (gn >= 0) xv = ((const float4*)(h + (size_t)gn * DIM))[c4];
        ((float4*)&xs[row][0])[c4] = xv;
    }

    const float* Ws[3] = { Wk + (size_t)ty * DIM * DIM,
                           Wq + (size_t)ty * DIM * DIM,
                           Wv + (size_t)ty * DIM * DIM };
    unsigned short* Os[3] = { kvbf, qbf, kvbf + 64 };
    const size_t   st[3] = { 128, 64, 128 };

    int og  = t & 15;
    int ng4 = (t >> 4) * 4;
    int g[4];
    #pragma unroll
    for (int j = 0; j < 4; j++) g[j] = order[n0 + ng4 + j];

    for (int mm = 0; mm < 3; mm++) {
        const float4* wg = (const float4*)Ws[mm];
        float4* wl = (float4*)&wsm[0][0];
        __syncthreads();
        #pragma unroll
        for (int i = 0; i < 4; i++) wl[t + 256 * i] = wg[t + 256 * i];
        __syncthreads();
        float4 a[4];
        #pragma unroll
        for (int j = 0; j < 4; j++) a[j] = make_float4(0.f, 0.f, 0.f, 0.f);
        #pragma unroll 8
        for (int d = 0; d < DIM; d++) {
            float4 wv = ((const float4*)&wsm[d][0])[og];
            #pragma unroll
            for (int j = 0; j < 4; j++) {
                float xx = xs[ng4 + j][d];
                a[j].x = fmaf(xx, wv.x, a[j].x); a[j].y = fmaf(xx, wv.y, a[j].y);
                a[j].z = fmaf(xx, wv.z, a[j].z); a[j].w = fmaf(xx, wv.w, a[j].w);
            }
        }
        unsigned short* ob = Os[mm];
        #pragma unroll
        for (int j = 0; j < 4; j++)
            if (g[j] >= 0)
                ((ushort4*)(ob + (size_t)g[j] * st[mm]))[og] =
                    make_ushort4(f2bf(a[j].x), f2bf(a[j].y), f2bf(a[j].z), f2bf(a[j].w));
    }
}

// ---- transpose + cast relation matrices: Wt[r][n][k] = bf16(W[r][k][n]) ----
__global__ void prep_w(const float* __restrict__ A, const float* __restrict__ Mw,
                       unsigned short* __restrict__ At, unsigned short* __restrict__ Mt) {
    int i = blockIdx.x * blockDim.x + threadIdx.x;
    if (i >= NR * DIM * DIM) return;
    int r = i >> 12;
    int idx = i & 4095;
    int n = idx >> 6;
    int k = idx & 63;
    At[i] = f2bf(A[(r << 12) + k * DIM + n]);
    Mt[i] = f2bf(Mw[(r << 12) + k * DIM + n]);
}

// ---------------- CSR build over (dst*8 + etype) buckets ----------------
__global__ void hist8(const int* __restrict__ dst, const int* __restrict__ et,
                      int* __restrict__ cnt, int E) {
    int e = blockIdx.x * blockDim.x + threadIdx.x;
    if (e < E) atomicAdd(&cnt[dst[e] * NR + et[e]], 1);
}

__global__ void scan1(const int* __restrict__ cnt, int* __restrict__ off,
                      int* __restrict__ bsum, int M) {
    __shared__ int buf[1024];
    int tid = threadIdx.x;
    int i = blockIdx.x * 1024 + tid;
    int x = (i < M) ? cnt[i] : 0;
    buf[tid] = x;
    __syncthreads();
    for (int s = 1; s < 1024; s <<= 1) {
        int t = (tid >= s) ? buf[tid - s] : 0;
        __syncthreads();
        buf[tid] += t;
        __syncthreads();
    }
    if (i < M) off[i] = buf[tid] - x;
    if (tid == 1023) bsum[blockIdx.x] = buf[1023];
}

__global__ void scan2(int* __restrict__ bsum, int nb) {
    __shared__ int buf[1024];
    __shared__ int carry;
    int tid = threadIdx.x;
    if (tid == 0) carry = 0;
    __syncthreads();
    for (int base = 0; base < nb; base += 1024) {
        int i = base + tid;
        int x = (i < nb) ? bsum[i] : 0;
        buf[tid] = x;
        __syncthreads();
        for (int s = 1; s < 1024; s <<= 1) {
            int t = (tid >= s) ? buf[tid - s] : 0;
            __syncthreads();
            buf[tid] += t;
            __syncthreads();
        }
        if (i < nb) bsum[i] = carry + buf[tid] - x;
        __syncthreads();
        if (tid == 1023) carry += buf[1023];
        __syncthreads();
    }
}

__global__ void scan3(int* __restrict__ off, const int* __restrict__ bsum, int M, int E) {
    int i = blockIdx.x * 1024 + threadIdx.x;
    if (i < M) off[i] += bsum[blockIdx.x];
    if (i == 0) off[M] = E;
}

__global__ void scatter8(const int* __restrict__ src, const int* __restrict__ dst,
                         const int* __restrict__ et, const int* __restrict__ off,
                         int* __restrict__ cnt2, int* __restrict__ se, int E) {
    int e = blockIdx.x * blockDim.x + threadIdx.x;
    if (e >= E) return;
    int key = dst[e] * NR + et[e];
    int p = off[key] + atomicAdd(&cnt2[key], 1);
    se[p] = src[e];
}

// =====================================================================
// Fused edge phase v2: one wave owns 16 dst nodes; zero block barriers.
//  - bucket offsets hoisted (lane m<9 holds off8[n*8+m]; i0/i1 via shfl)
//  - dual-edge half-groups: lanes 0-7 = edge A, 8-15 = edge B; each lane
//    owns 8 dims via one ushort8 load from interleaved kv[n][128]
//  - walk unrolled 2 pairs deep: up to 4 edges (8 gathers) in flight
// Per relation r: qW tile via MFMA; walk; U += P @ M_r via MFMA.
// =====================================================================
__global__ void __launch_bounds__(256)
fused_edge(const unsigned short* __restrict__ qbf,
           const unsigned short* __restrict__ kvbf,
           const unsigned short* __restrict__ At,
           const unsigned short* __restrict__ Mt,
           const int* __restrict__ se, const int* __restrict__ off8,
           const float* __restrict__ rel_pri,
           float* __restrict__ agg, int N) {
    __shared__ __align__(16) float qw[4][16][68];           // per-wave qW tile (f32)
    __shared__ __align__(16) unsigned short pl[4][16][72];  // per-wave P tile (bf16)
    const int t    = threadIdx.x;
    const int wave = t >> 6;
    const int m    = t & 15;         // MFMA col / lane-in-group
    const int quad = (t >> 4) & 3;   // MFMA quad == walk group
    const int half = m >> 3;         // 0: edge A, 1: edge B
    const int oct  = m & 7;          // dim-octet owner: dims oct*8 .. oct*8+7
    const int n0   = blockIdx.x * 64 + wave * 16;
    if (n0 >= N) return;

    // Q A-frags, held across all r
    bf16x8 qa0 = {0,0,0,0,0,0,0,0}, qa1 = {0,0,0,0,0,0,0,0};
    {
        const int gn = n0 + m;
        if (gn < N) {
            const unsigned short* qp = qbf + ((size_t)gn << 6) + quad * 8;
            qa0 = *((const bf16x8*)qp);
            qa1 = *((const bf16x8*)(qp + 32));
        }
    }

    // hoisted bucket offsets: group-lane m holds off8[n_j*8 + m] (m<9)
    int ov[4];
    #pragma unroll
    for (int j = 0; j < 4; j++) {
        const int nj = n0 + quad * 4 + j;
        ov[j] = (m < 9 && nj < N) ? off8[nj * NR + m] : 0;
    }

    f32x4 u0 = {0.f,0.f,0.f,0.f}, u1 = u0, u2 = u0, u3 = u0;  // U accumulator
    float d0 = 0.f, d1 = 0.f, d2 = 0.f, d3 = 0.f;             // denominators

    for (int r = 0; r < NR; r++) {
        // ---- qW tile via MFMA ----
        const unsigned short* Ar = At + ((size_t)r << 12);
        f32x4 c0 = {0.f,0.f,0.f,0.f}, c1 = c0, c2 = c0, c3 = c0;
        c0 = __builtin_amdgcn_mfma_f32_16x16x32_bf16(qa0, ldb16(Ar + (( 0 + m) << 6)      + quad * 8), c0, 0, 0, 0);
        c1 = __builtin_amdgcn_mfma_f32_16x16x32_bf16(qa0, ldb16(Ar + ((16 + m) << 6)      + quad * 8), c1, 0, 0, 0);
        c2 = __builtin_amdgcn_mfma_f32_16x16x32_bf16(qa0, ldb16(Ar + ((32 + m) << 6)      + quad * 8), c2, 0, 0, 0);
        c3 = __builtin_amdgcn_mfma_f32_16x16x32_bf16(qa0, ldb16(Ar + ((48 + m) << 6)      + quad * 8), c3, 0, 0, 0);
        c0 = __builtin_amdgcn_mfma_f32_16x16x32_bf16(qa1, ldb16(Ar + (( 0 + m) << 6) + 32 + quad * 8), c0, 0, 0, 0);
        c1 = __builtin_amdgcn_mfma_f32_16x16x32_bf16(qa1, ldb16(Ar + ((16 + m) << 6) + 32 + quad * 8), c1, 0, 0, 0);
        c2 = __builtin_amdgcn_mfma_f32_16x16x32_bf16(qa1, ldb16(Ar + ((32 + m) << 6) + 32 + quad * 8), c2, 0, 0, 0);
        c3 = __builtin_amdgcn_mfma_f32_16x16x32_bf16(qa1, ldb16(Ar + ((48 + m) << 6) + 32 + quad * 8), c3, 0, 0, 0);

        #pragma unroll
        for (int reg = 0; reg < 4; reg++) {
            float* qr = &qw[wave][quad * 4 + reg][m];
            qr[ 0] = c0[reg]; qr[16] = c1[reg]; qr[32] = c2[reg]; qr[48] = c3[reg];
        }
        asm volatile("s_waitcnt lgkmcnt(0)" ::: "memory");

        // ---- dual-edge walk ----
        const float pri = rel_pri[r] * 0.125f;
        #pragma unroll
        for (int j = 0; j < 4; j++) {
            const int i0 = __shfl(ov[j], r, 16);
            const int i1 = __shfl(ov[j], r + 1, 16);
            float dd = 0.f;
            float4 pa = make_float4(0.f, 0.f, 0.f, 0.f);
            float4 pb = make_float4(0.f, 0.f, 0.f, 0.f);
            if (i0 < i1) {
                const float4 tva = *((const float4*)&qw[wave][quad * 4 + j][oct * 8]);
                const float4 tvb = *((const float4*)&qw[wave][quad * 4 + j][oct * 8 + 4]);
                auto edge2 = [&](int base) {
                    const int idx  = base + half;
                    const bool val = idx < i1;
                    const int s    = se[val ? idx : i0];
                    const unsigned short* kvp = kvbf + ((size_t)s << 7) + oct * 8;
                    const u16x8 k8 = *((const u16x8*)kvp);
                    const u16x8 v8 = *((const u16x8*)(kvp + 64));
                    float p  = bf2f(k8[0]) * tva.x + bf2f(k8[1]) * tva.y +
                               bf2f(k8[2]) * tva.z + bf2f(k8[3]) * tva.w;
                    float p2 = bf2f(k8[4]) * tvb.x + bf2f(k8[5]) * tvb.y +
                               bf2f(k8[6]) * tvb.z + bf2f(k8[7]) * tvb.w;
                    p += p2;
                    p += __shfl_xor(p, 1, 16);
                    p += __shfl_xor(p, 2, 16);
                    p += __shfl_xor(p, 4, 16);
                    const float e = val ? __expf(p * pri) : 0.f;
                    dd += e;
                    pa.x = fmaf(e, bf2f(v8[0]), pa.x);
                    pa.y = fmaf(e, bf2f(v8[1]), pa.y);
                    pa.z = fmaf(e, bf2f(v8[2]), pa.z);
                    pa.w = fmaf(e, bf2f(v8[3]), pa.w);
                    pb.x = fmaf(e, bf2f(v8[4]), pb.x);
                    pb.y = fmaf(e, bf2f(v8[5]), pb.y);
                    pb.z = fmaf(e, bf2f(v8[6]), pb.z);
                    pb.w = fmaf(e, bf2f(v8[7]), pb.w);
                };
                int i = i0;
                for (; i + 2 < i1; i += 4) { edge2(i); edge2(i + 2); }
                for (; i < i1; i += 2) edge2(i);
                // merge the two half-group edges (different edges, same bucket)
                dd  += __shfl_xor(dd, 8, 16);
                pa.x += __shfl_xor(pa.x, 8, 16);
                pa.y += __shfl_xor(pa.y, 8, 16);
                pa.z += __shfl_xor(pa.z, 8, 16);
                pa.w += __shfl_xor(pa.w, 8, 16);
                pb.x += __shfl_xor(pb.x, 8, 16);
                pb.y += __shfl_xor(pb.y, 8, 16);
                pb.z += __shfl_xor(pb.z, 8, 16);
                pb.w += __shfl_xor(pb.w, 8, 16);
            }
            if (m < 8) {
                u16x8 w;
                w[0] = f2bf(pa.x); w[1] = f2bf(pa.y); w[2] = f2bf(pa.z); w[3] = f2bf(pa.w);
                w[4] = f2bf(pb.x); w[5] = f2bf(pb.y); w[6] = f2bf(pb.z); w[7] = f2bf(pb.w);
                *((u16x8*)&pl[wave][quad * 4 + j][m * 8]) = w;
            }
            if      (j == 0) d0 += dd;
            else if (j == 1) d1 += dd;
            else if (j == 2) d2 += dd;
            else             d3 += dd;
        }
        asm volatile("s_waitcnt lgkmcnt(0)" ::: "memory");

        // ---- U += P @ M_r ----
        const unsigned short* Mr = Mt + ((size_t)r << 12);
        const bf16x8 pa0 = *((const bf16x8*)&pl[wave][m][quad * 8]);
        const bf16x8 pa1 = *((const bf16x8*)&pl[wave][m][32 + quad * 8]);
        u0 = __builtin_amdgcn_mfma_f32_16x16x32_bf16(pa0, ldb16(Mr + (( 0 + m) << 6)      + quad * 8), u0, 0, 0, 0);
        u1 = __builtin_amdgcn_mfma_f32_16x16x32_bf16(pa0, ldb16(Mr + ((16 + m) << 6)      + quad * 8), u1, 0, 0, 0);
        u2 = __builtin_amdgcn_mfma_f32_16x16x32_bf16(pa0, ldb16(Mr + ((32 + m) << 6)      + quad * 8), u2, 0, 0, 0);
        u3 = __builtin_amdgcn_mfma_f32_16x16x32_bf16(pa0, ldb16(Mr + ((48 + m) << 6)      + quad * 8), u3, 0, 0, 0);
        u0 = __builtin_amdgcn_mfma_f32_16x16x32_bf16(pa1, ldb16(Mr + (( 0 + m) << 6) + 32 + quad * 8), u0, 0, 0, 0);
        u1 = __builtin_amdgcn_mfma_f32_16x16x32_bf16(pa1, ldb16(Mr + ((16 + m) << 6) + 32 + quad * 8), u1, 0, 0, 0);
        u2 = __builtin_amdgcn_mfma_f32_16x16x32_bf16(pa1, ldb16(Mr + ((32 + m) << 6) + 32 + quad * 8), u2, 0, 0, 0);
        u3 = __builtin_amdgcn_mfma_f32_16x16x32_bf16(pa1, ldb16(Mr + ((48 + m) << 6) + 32 + quad * 8), u3, 0, 0, 0);
        asm volatile("s_waitcnt lgkmcnt(0)" ::: "memory");
    }

    // ---- epilogue: agg[n] = U[n] / D[n] ----
    #pragma unroll
    for (int reg = 0; reg < 4; reg++) {
        const int n = n0 + quad * 4 + reg;
        if (n >= N) continue;
        const float dv  = (reg == 0) ? d0 : (reg == 1) ? d1 : (reg == 2) ? d2 : d3;
        const float inv = (dv == 0.f) ? 0.f : 1.f / dv;
        float* rowp = agg + ((size_t)n << 6) + m;
        rowp[ 0] = u0[reg] * inv;
        rowp[16] = u1[reg] * inv;
        rowp[32] = u2[reg] * inv;
        rowp[48] = u3[reg] * inv;
    }
}

// ------- typed output GEMM: 64-node tile, sigmoid(skip)*W staged in LDS -------
__global__ void out_typed(const float* __restrict__ agg, const int* __restrict__ ntype,
                          const int* __restrict__ order, const int* __restrict__ tm,
                          const float* __restrict__ Wa, const float* __restrict__ skip,
                          float* __restrict__ out, int N) {
    __shared__ float xs[64][68];
    __shared__ float wsm[64][64];
    int t  = threadIdx.x;
    int n0 = blockIdx.x * 64;
    if (n0 >= tm[12]) return;
    int first = order[n0];
    if (first < 0) return;
    int ty = ntype[first];
    float sg = 1.f / (1.f + expf(-skip[ty]));

    const float4* wg = (const float4*)(Wa + (size_t)ty * DIM * DIM);
    float4* wl = (float4*)&wsm[0][0];
    #pragma unroll
    for (int i = 0; i < 4; i++) {
        float4 w = wg[t + 256 * i];
        w.x *= sg; w.y *= sg; w.z *= sg; w.w *= sg;
        wl[t + 256 * i] = w;
    }
    #pragma unroll
    for (int i = 0; i < 4; i++) {
        int idx = t + 256 * i;
        int row = idx >> 4, c4 = idx & 15;
        int gn = order[n0 + row];
        float4 xv = make_float4(0.f, 0.f, 0.f, 0.f);
        if (gn >= 0) xv = ((const float4*)(agg + (size_t)gn * DIM))[c4];
        ((float4*)&xs[row][0])[c4] = xv;
    }
    __syncthreads();

    int og  = t & 15;
    int ng4 = (t >> 4) * 4;
    float4 a0 = make_float4(0.f,0.f,0.f,0.f), a1 = a0, a2 = a0, a3 = a0;
    #pragma unroll 8
    for (int d = 0; d < DIM; d++) {
        float4 wv = ((const float4*)&wsm[d][0])[og];
        float x0 = xs[ng4 + 0][d];
        float x1 = xs[ng4 + 1][d];
        float x2 = xs[ng4 + 2][d];
        float x3 = xs[ng4 + 3][d];
        a0.x = fmaf(x0, wv.x, a0.x); a0.y = fmaf(x0, wv.y, a0.y);
        a0.z = fmaf(x0, wv.z, a0.z); a0.w = fmaf(x0, wv.w, a0.w);
        a1.x = fmaf(x1, wv.x, a1.x); a1.y = fmaf(x1, wv.y, a1.y);
        a1.z = fmaf(x1, wv.z, a1.z); a1.w = fmaf(x1, wv.w, a1.w);
        a2.x = fmaf(x2, wv.x, a2.x); a2.y = fmaf(x2, wv.y, a2.y);
        a2.z = fmaf(x2, wv.z, a2.z); a2.w = fmaf(x2, wv.w, a2.w);
        a3.x = fmaf(x3, wv.x, a3.x); a3.y = fmaf(x3, wv.y, a3.y);
        a3.z = fmaf(x3, wv.z, a3.z); a3.w = fmaf(x3, wv.w, a3.w);
    }
    int g0 = order[n0 + ng4 + 0];
    int g1 = order[n0 + ng4 + 1];
    int g2 = order[n0 + ng4 + 2];
    int g3 = order[n0 + ng4 + 3];
    if (g0 >= 0) ((float4*)(out + (size_t)g0 * DIM))[og] = a0;
    if (g1 >= 0) ((float4*)(out + (size_t)g1 * DIM))[og] = a1;
    if (g2 >= 0) ((float4*)(out + (size_t)g2 * DIM))[og] = a2;
    if (g3 >= 0) ((float4*)(out + (size_t)g3 * DIM))[og] = a3;
}

extern "C" void kernel_launch(void* const* d_in, const int* in_sizes, int n_in,
                              void* d_out, int out_size, void* d_ws, size_t ws_size,
                              hipStream_t stream) {
    const float* h       = (const float*)d_in[0];
    const int*   ntype   = (const int*)  d_in[1];
    const int*   src     = (const int*)  d_in[2];
    const int*   dst     = (const int*)  d_in[3];
    const int*   et      = (const int*)  d_in[4];
    const float* k_lin   = (const float*)d_in[5];
    const float* q_lin   = (const float*)d_in[6];
    const float* v_lin   = (const float*)d_in[7];
    const float* a_lin   = (const float*)d_in[8];
    const float* rel_att = (const float*)d_in[9];
    const float* rel_msg = (const float*)d_in[10];
    const float* rel_pri = (const float*)d_in[11];
    const float* skip    = (const float*)d_in[12];

    int N = in_sizes[1];
    int E = in_sizes[2];
    int M = N * NR;
    int ocap = N + NT * 64;

    float* ws = (float*)d_ws;
    size_t o = 0;
    unsigned short* kvbf = (unsigned short*)(ws + o); o += (size_t)N * DIM;      // kv[n][128] bf16
    unsigned short* qbf  = (unsigned short*)(ws + o); o += (size_t)N * DIM / 2;
    float* agg  = ws + o; o += (size_t)N * DIM;
    int* off8   = (int*)(ws + o); o += (size_t)M + 8;
    int* cnt8   = (int*)(ws + o); o += (size_t)M;
    int* cnt28  = (int*)(ws + o); o += (size_t)M;   // contiguous with cnt8
    int* se     = (int*)(ws + o); o += (size_t)E;
    int* bsum   = (int*)(ws + o); o += 1024;
    int* order  = (int*)(ws + o); o += (size_t)ocap;
    int* tm     = (int*)(ws + o); o += 16;
    unsigned short* At = (unsigned short*)(ws + o); o += (size_t)NR * DIM * DIM / 2;
    unsigned short* Mt = (unsigned short*)(ws + o); o += (size_t)NR * DIM * DIM / 2;

    float* out = (float*)d_out;

    // ---- zero-init via memset nodes (capture-legal, fewer launches) ----
    hipMemsetAsync(order, 0xFF, (size_t)ocap * 4, stream);      // -1 fill
    hipMemsetAsync(tm, 0, 16 * 4, stream);
    hipMemsetAsync(cnt8, 0, (size_t)2 * M * 4, stream);         // cnt8 + cnt28

    // ---- type sort ----
    type_count<<<(N + 255) / 256, 256, 0, stream>>>(ntype, tm, N);
    type_scan<<<1, 64, 0, stream>>>(tm);
    type_scatter<<<(N + 255) / 256, 256, 0, stream>>>(ntype, tm, order, N);

    // ---- typed fused projections (k,v -> interleaved kv bf16; q -> bf16) ----
    int gridT = (N + NT * 64 + 63) / 64;
    proj_typed<<<gridT, 256, 0, stream>>>(h, ntype, order, tm, k_lin, q_lin, v_lin,
                                          kvbf, qbf, N);

    // ---- relation weight transpose+cast (for MFMA B-operand) ----
    prep_w<<<(NR * DIM * DIM + 255) / 256, 256, 0, stream>>>(rel_att, rel_msg, At, Mt);

    // ---- CSR build over (dst, etype) buckets ----
    hist8<<<(E + 255) / 256, 256, 0, stream>>>(dst, et, cnt8, E);
    int nb = (M + 1023) / 1024;
    scan1<<<nb, 1024, 0, stream>>>(cnt8, off8, bsum, M);
    scan2<<<1, 1024, 0, stream>>>(bsum, nb);
    scan3<<<nb, 1024, 0, stream>>>(off8, bsum, M, E);
    scatter8<<<(E + 255) / 256, 256, 0, stream>>>(src, dst, et, off8, cnt28, se, E);

    // ---- fused edge phase ----
    int nb64 = (N + 63) / 64;
    fused_edge<<<nb64, 256, 0, stream>>>(qbf, kvbf, At, Mt, se, off8,
                                         rel_pri, agg, N);

    // ---- typed output GEMM ----
    out_typed<<<gridT, 256, 0, stream>>>(agg, ntype, order, tm, a_lin, skip, out, N);
}

// Round 3
// 654.725 us; speedup vs baseline: 1.0960x; 1.0504x over previous
//
#include <hip/hip_runtime.h>
#include <math.h>

#define DIM 64
#define NT 4
#define NR 8
// tmeta layout: [0..3]=tcnt  [4..7]=tbase  [8..11]=tfill  [12]=padded_total

typedef __attribute__((ext_vector_type(8))) short bf16x8;   // 8 bf16 (4 VGPRs)
typedef __attribute__((ext_vector_type(8))) unsigned short u16x8;
typedef __attribute__((ext_vector_type(4))) float f32x4;    // 4 fp32 acc

// ---- bf16 helpers (bit-level; values finite/small) ----
__device__ __forceinline__ unsigned short f2bf(float f) {
    unsigned u = __float_as_uint(f);
    return (unsigned short)((u + 0x7FFF + ((u >> 16) & 1)) >> 16);  // RNE
}
__device__ __forceinline__ float bf2f(unsigned short u) {
    return __uint_as_float((unsigned)u << 16);
}
__device__ __forceinline__ bf16x8 ldb16(const unsigned short* p) {
    return *((const bf16x8*)p);
}

// ---- per-wave ballot histogram of node types ----
__global__ void type_count(const int* __restrict__ ntype, int* __restrict__ tm, int N) {
    int i = blockIdx.x * blockDim.x + threadIdx.x;
    int t = (i < N) ? ntype[i] : -1;
    int lane = threadIdx.x & 63;
    #pragma unroll
    for (int tt = 0; tt < NT; tt++) {
        unsigned long long m = __ballot(t == tt);
        int c = __popcll(m);
        if (c && lane == (__ffsll((long long)m) - 1)) atomicAdd(&tm[tt], c);
    }
}

__global__ void type_scan(int* __restrict__ tm) {
    if (threadIdx.x == 0 && blockIdx.x == 0) {
        int b = 0;
        for (int t = 0; t < NT; t++) { tm[4 + t] = b; b += ((tm[t] + 63) >> 6) << 6; }
        tm[12] = b;
    }
}

__global__ void type_scatter(const int* __restrict__ ntype, int* __restrict__ tm,
                             int* __restrict__ order, int N) {
    int i = blockIdx.x * blockDim.x + threadIdx.x;
    int t = (i < N) ? ntype[i] : -1;
    int lane = threadIdx.x & 63;
    #pragma unroll
    for (int tt = 0; tt < NT; tt++) {
        unsigned long long m = __ballot(t == tt);
        int c = __popcll(m);
        if (!c) continue;
        int ldr = __ffsll((long long)m) - 1;
        int base = 0;
        if (lane == ldr) base = atomicAdd(&tm[8 + tt], c);
        base = __shfl(base, ldr, 64);
        if (t == tt) {
            int rank = __popcll(m & ((1ull << lane) - 1ull));
            order[tm[4 + tt] + base + rank] = i;
        }
    }
}

// ---- transpose+cast ALL weight matrices to bf16 [mat][n][k] layout ----
// mats: 0..7 = rel_att, 8..15 = rel_msg, 16..19 = k_lin, 20..23 = q_lin, 24..27 = v_lin
__global__ void prep_all(const float* __restrict__ A, const float* __restrict__ Mw,
                         const float* __restrict__ kl, const float* __restrict__ ql,
                         const float* __restrict__ vl,
                         unsigned short* __restrict__ At, unsigned short* __restrict__ Mt,
                         unsigned short* __restrict__ Wkt, unsigned short* __restrict__ Wqt,
                         unsigned short* __restrict__ Wvt) {
    int i = blockIdx.x * blockDim.x + threadIdx.x;
    if (i >= 28 * DIM * DIM) return;
    int mat = i >> 12;
    int idx = i & 4095;
    int n = idx >> 6;
    int k = idx & 63;
    int so = k * DIM + n;
    if (mat < 8)       At [((size_t)mat << 12) + idx]        = f2bf(A [((size_t)mat << 12) + so]);
    else if (mat < 16) Mt [((size_t)(mat - 8) << 12) + idx]  = f2bf(Mw[((size_t)(mat - 8) << 12) + so]);
    else if (mat < 20) Wkt[((size_t)(mat - 16) << 12) + idx] = f2bf(kl[((size_t)(mat - 16) << 12) + so]);
    else if (mat < 24) Wqt[((size_t)(mat - 20) << 12) + idx] = f2bf(ql[((size_t)(mat - 20) << 12) + so]);
    else               Wvt[((size_t)(mat - 24) << 12) + idx] = f2bf(vl[((size_t)(mat - 24) << 12) + so]);
}

// ---- typed K/Q/V projection via MFMA: 64-node tile; k,v interleaved kv[n][128] ----
__global__ void __launch_bounds__(256)
proj_mfma(const float* __restrict__ h, const int* __restrict__ ntype,
          const int* __restrict__ order, const int* __restrict__ tm,
          const unsigned short* __restrict__ Wkt, const unsigned short* __restrict__ Wqt,
          const unsigned short* __restrict__ Wvt,
          unsigned short* __restrict__ kvbf, unsigned short* __restrict__ qbf, int N) {
    __shared__ __align__(16) unsigned short xs[64][72];
    int t  = threadIdx.x;
    int n0 = blockIdx.x * 64;
    if (n0 >= tm[12]) return;
    int first = order[n0];
    if (first < 0) return;
    int ty = ntype[first];

    // stage h tile as bf16
    #pragma unroll
    for (int i = 0; i < 4; i++) {
        int idx = t + 256 * i;
        int row = idx >> 4, c4 = idx & 15;
        int gn = order[n0 + row];
        float4 xv = make_float4(0.f, 0.f, 0.f, 0.f);
        if (gn >= 0) xv = ((const float4*)(h + (size_t)gn * DIM))[c4];
        ushort4 b = make_ushort4(f2bf(xv.x), f2bf(xv.y), f2bf(xv.z), f2bf(xv.w));
        *((ushort4*)&xs[row][c4 * 4]) = b;
    }
    __syncthreads();

    int wave = t >> 6, lane = t & 63;
    int m = lane & 15, quad = lane >> 4;
    bf16x8 xa0 = *((const bf16x8*)&xs[wave * 16 + m][quad * 8]);
    bf16x8 xa1 = *((const bf16x8*)&xs[wave * 16 + m][32 + quad * 8]);

    int g[4];
    #pragma unroll
    for (int reg = 0; reg < 4; reg++) g[reg] = order[n0 + wave * 16 + quad * 4 + reg];

    const unsigned short* Wt[3] = { Wkt + (size_t)ty * 4096,
                                    Wqt + (size_t)ty * 4096,
                                    Wvt + (size_t)ty * 4096 };
    for (int mm = 0; mm < 3; mm++) {
        const unsigned short* W = Wt[mm];
        f32x4 c0 = {0.f,0.f,0.f,0.f}, c1 = c0, c2 = c0, c3 = c0;
        c0 = __builtin_amdgcn_mfma_f32_16x16x32_bf16(xa0, ldb16(W + (( 0 + m) << 6)      + quad * 8), c0, 0, 0, 0);
        c1 = __builtin_amdgcn_mfma_f32_16x16x32_bf16(xa0, ldb16(W + ((16 + m) << 6)      + quad * 8), c1, 0, 0, 0);
        c2 = __builtin_amdgcn_mfma_f32_16x16x32_bf16(xa0, ldb16(W + ((32 + m) << 6)      + quad * 8), c2, 0, 0, 0);
        c3 = __builtin_amdgcn_mfma_f32_16x16x32_bf16(xa0, ldb16(W + ((48 + m) << 6)      + quad * 8), c3, 0, 0, 0);
        c0 = __builtin_amdgcn_mfma_f32_16x16x32_bf16(xa1, ldb16(W + (( 0 + m) << 6) + 32 + quad * 8), c0, 0, 0, 0);
        c1 = __builtin_amdgcn_mfma_f32_16x16x32_bf16(xa1, ldb16(W + ((16 + m) << 6) + 32 + quad * 8), c1, 0, 0, 0);
        c2 = __builtin_amdgcn_mfma_f32_16x16x32_bf16(xa1, ldb16(W + ((32 + m) << 6) + 32 + quad * 8), c2, 0, 0, 0);
        c3 = __builtin_amdgcn_mfma_f32_16x16x32_bf16(xa1, ldb16(W + ((48 + m) << 6) + 32 + quad * 8), c3, 0, 0, 0);

        // D: row = quad*4+reg (node), col = m + 16*nb
        #pragma unroll
        for (int reg = 0; reg < 4; reg++) {
            if (g[reg] < 0) continue;
            unsigned short* row;
            if (mm == 1)       row = qbf  + ((size_t)g[reg] << 6) + m;
            else if (mm == 0)  row = kvbf + ((size_t)g[reg] << 7) + m;
            else               row = kvbf + ((size_t)g[reg] << 7) + 64 + m;
            row[ 0] = f2bf(c0[reg]);
            row[16] = f2bf(c1[reg]);
            row[32] = f2bf(c2[reg]);
            row[48] = f2bf(c3[reg]);
        }
    }
}

// ---------------- CSR build over (dst*8 + etype) buckets ----------------
__global__ void hist8(const int* __restrict__ dst, const int* __restrict__ et,
                      int* __restrict__ cnt, int E) {
    int e = blockIdx.x * blockDim.x + threadIdx.x;
    if (e < E) atomicAdd(&cnt[dst[e] * NR + et[e]], 1);
}

__global__ void scan1(const int* __restrict__ cnt, int* __restrict__ off,
                      int* __restrict__ bsum, int M) {
    __shared__ int buf[1024];
    int tid = threadIdx.x;
    int i = blockIdx.x * 1024 + tid;
    int x = (i < M) ? cnt[i] : 0;
    buf[tid] = x;
    __syncthreads();
    for (int s = 1; s < 1024; s <<= 1) {
        int t = (tid >= s) ? buf[tid - s] : 0;
        __syncthreads();
        buf[tid] += t;
        __syncthreads();
    }
    if (i < M) off[i] = buf[tid] - x;
    if (tid == 1023) bsum[blockIdx.x] = buf[1023];
}

__global__ void scan2(int* __restrict__ bsum, int nb) {
    __shared__ int buf[1024];
    __shared__ int carry;
    int tid = threadIdx.x;
    if (tid == 0) carry = 0;
    __syncthreads();
    for (int base = 0; base < nb; base += 1024) {
        int i = base + tid;
        int x = (i < nb) ? bsum[i] : 0;
        buf[tid] = x;
        __syncthreads();
        for (int s = 1; s < 1024; s <<= 1) {
            int t = (tid >= s) ? buf[tid - s] : 0;
            __syncthreads();
            buf[tid] += t;
            __syncthreads();
        }
        if (i < nb) bsum[i] = carry + buf[tid] - x;
        __syncthreads();
        if (tid == 1023) carry += buf[1023];
        __syncthreads();
    }
}

__global__ void scan3(int* __restrict__ off, const int* __restrict__ bsum, int M, int E) {
    int i = blockIdx.x * 1024 + threadIdx.x;
    if (i < M) off[i] += bsum[blockIdx.x];
    if (i == 0) off[M] = E;
}

__global__ void scatter8(const int* __restrict__ src, const int* __restrict__ dst,
                         const int* __restrict__ et, const int* __restrict__ off,
                         int* __restrict__ cnt2, int* __restrict__ se, int E) {
    int e = blockIdx.x * blockDim.x + threadIdx.x;
    if (e >= E) return;
    int key = dst[e] * NR + et[e];
    int p = off[key] + atomicAdd(&cnt2[key], 1);
    se[p] = src[e];
}

// =====================================================================
// Fused edge phase v3: one wave owns 16 dst nodes; zero block barriers.
// MFMA phases use (m=lane&15, quad=lane>>4) roles; the WALK re-partitions
// the wave into 16 subgroups of 4 lanes: subgroup sg = lane>>2 owns node
// sg, lane ll = lane&3 owns dims ll*16..ll*16+15. All 16 nodes' buckets
// for relation r walk CONCURRENTLY (16 independent gather streams/wave),
// with even/odd edge streams merged in-register (no merge shuffles) and
// a 2-shuffle score reduce. Bucket offsets hoisted once per wave.
// =====================================================================
__global__ void __launch_bounds__(256)
fused_edge(const unsigned short* __restrict__ qbf,
           const unsigned short* __restrict__ kvbf,
           const unsigned short* __restrict__ At,
           const unsigned short* __restrict__ Mt,
           const int* __restrict__ se, const int* __restrict__ off8,
           const float* __restrict__ rel_pri,
           float* __restrict__ agg, int N) {
    __shared__ __align__(16) unsigned short qwb[4][16][72];  // per-wave qW tile (bf16)
    __shared__ __align__(16) unsigned short pl[4][16][72];   // per-wave P tile (bf16)
    const int t    = threadIdx.x;
    const int wave = t >> 6;
    const int lane = t & 63;
    const int m    = lane & 15;      // MFMA col
    const int quad = lane >> 4;      // MFMA quad
    const int sg   = lane >> 2;      // walk: node owner (0..15)
    const int ll   = lane & 3;       // walk: dim-16 owner
    const int n0   = blockIdx.x * 64 + wave * 16;
    if (n0 >= N) return;

    // Q A-frags, held across all r
    bf16x8 qa0 = {0,0,0,0,0,0,0,0}, qa1 = {0,0,0,0,0,0,0,0};
    {
        const int gn = n0 + m;
        if (gn < N) {
            const unsigned short* qp = qbf + ((size_t)gn << 6) + quad * 8;
            qa0 = *((const bf16x8*)qp);
            qa1 = *((const bf16x8*)(qp + 32));
        }
    }

    // hoisted bucket offsets: 129 values for the wave's 16 nodes
    const int ob = n0 * NR;
    const int ov0 = off8[ob + lane];
    const int ov1 = off8[ob + 64 + lane];
    const int ov2 = off8[ob + 128];
    const bool act = (n0 + sg) < N;

    f32x4 u0 = {0.f,0.f,0.f,0.f}, u1 = u0, u2 = u0, u3 = u0;  // U accumulator
    float ddsum = 0.f;   // node sg's denominator (replicated over 4 lanes)

    for (int r = 0; r < NR; r++) {
        // ---- qW tile via MFMA ----
        const unsigned short* Ar = At + ((size_t)r << 12);
        f32x4 c0 = {0.f,0.f,0.f,0.f}, c1 = c0, c2 = c0, c3 = c0;
        c0 = __builtin_amdgcn_mfma_f32_16x16x32_bf16(qa0, ldb16(Ar + (( 0 + m) << 6)      + quad * 8), c0, 0, 0, 0);
        c1 = __builtin_amdgcn_mfma_f32_16x16x32_bf16(qa0, ldb16(Ar + ((16 + m) << 6)      + quad * 8), c1, 0, 0, 0);
        c2 = __builtin_amdgcn_mfma_f32_16x16x32_bf16(qa0, ldb16(Ar + ((32 + m) << 6)      + quad * 8), c2, 0, 0, 0);
        c3 = __builtin_amdgcn_mfma_f32_16x16x32_bf16(qa0, ldb16(Ar + ((48 + m) << 6)      + quad * 8), c3, 0, 0, 0);
        c0 = __builtin_amdgcn_mfma_f32_16x16x32_bf16(qa1, ldb16(Ar + (( 0 + m) << 6) + 32 + quad * 8), c0, 0, 0, 0);
        c1 = __builtin_amdgcn_mfma_f32_16x16x32_bf16(qa1, ldb16(Ar + ((16 + m) << 6) + 32 + quad * 8), c1, 0, 0, 0);
        c2 = __builtin_amdgcn_mfma_f32_16x16x32_bf16(qa1, ldb16(Ar + ((32 + m) << 6) + 32 + quad * 8), c2, 0, 0, 0);
        c3 = __builtin_amdgcn_mfma_f32_16x16x32_bf16(qa1, ldb16(Ar + ((48 + m) << 6) + 32 + quad * 8), c3, 0, 0, 0);

        // scatter D (row=quad*4+reg, col=nb*16+m) to LDS as bf16
        #pragma unroll
        for (int reg = 0; reg < 4; reg++) {
            unsigned short* qr = &qwb[wave][quad * 4 + reg][m];
            qr[ 0] = f2bf(c0[reg]); qr[16] = f2bf(c1[reg]);
            qr[32] = f2bf(c2[reg]); qr[48] = f2bf(c3[reg]);
        }
        asm volatile("s_waitcnt lgkmcnt(0)" ::: "memory");

        // ---- parallel walk: 16 subgroups, one bucket each ----
        const int g  = sg * NR + r;
        const int g1 = g + 1;
        const int x0a = __shfl(ov0, g, 64);
        const int x0b = __shfl(ov1, g - 64, 64);
        int i0 = (g < 64) ? x0a : x0b;
        const int x1a = __shfl(ov0, g1, 64);
        const int x1b = __shfl(ov1, g1 - 64, 64);
        int i1 = (g1 < 64) ? x1a : ((g1 < 128) ? x1b : ov2);
        if (!act) i1 = i0;

        const float pri = rel_pri[r] * 0.125f;
        float pe[16], po[16];
        #pragma unroll
        for (int x = 0; x < 16; x++) { pe[x] = 0.f; po[x] = 0.f; }
        float dde = 0.f, ddo = 0.f;

        if (i0 < i1) {
            const u16x8 tq0 = *((const u16x8*)&qwb[wave][sg][ll * 16]);
            const u16x8 tq1 = *((const u16x8*)&qwb[wave][sg][ll * 16 + 8]);
            float tq[16];
            #pragma unroll
            for (int x = 0; x < 8; x++) { tq[x] = bf2f(tq0[x]); tq[8 + x] = bf2f(tq1[x]); }

            for (int i = i0; i < i1; i += 2) {
                const int sA = se[i];
                const bool hB = (i + 1 < i1);
                const int sB = se[hB ? i + 1 : i];
                const unsigned short* pA = kvbf + ((size_t)sA << 7) + ll * 16;
                const unsigned short* pB = kvbf + ((size_t)sB << 7) + ll * 16;
                const u16x8 kA0 = *((const u16x8*)pA);
                const u16x8 kA1 = *((const u16x8*)(pA + 8));
                const u16x8 vA0 = *((const u16x8*)(pA + 64));
                const u16x8 vA1 = *((const u16x8*)(pA + 72));
                const u16x8 kB0 = *((const u16x8*)pB);
                const u16x8 kB1 = *((const u16x8*)(pB + 8));
                const u16x8 vB0 = *((const u16x8*)(pB + 64));
                const u16x8 vB1 = *((const u16x8*)(pB + 72));
                float sa = 0.f, sb = 0.f;
                #pragma unroll
                for (int x = 0; x < 8; x++) {
                    sa = fmaf(bf2f(kA0[x]), tq[x],     sa);
                    sa = fmaf(bf2f(kA1[x]), tq[8 + x], sa);
                    sb = fmaf(bf2f(kB0[x]), tq[x],     sb);
                    sb = fmaf(bf2f(kB1[x]), tq[8 + x], sb);
                }
                sa += __shfl_xor(sa, 1, 4);
                sa += __shfl_xor(sa, 2, 4);
                sb += __shfl_xor(sb, 1, 4);
                sb += __shfl_xor(sb, 2, 4);
                const float eA = __expf(sa * pri);
                const float eB = hB ? __expf(sb * pri) : 0.f;
                dde += eA; ddo += eB;
                #pragma unroll
                for (int x = 0; x < 8; x++) {
                    pe[x]     = fmaf(eA, bf2f(vA0[x]), pe[x]);
                    pe[8 + x] = fmaf(eA, bf2f(vA1[x]), pe[8 + x]);
                    po[x]     = fmaf(eB, bf2f(vB0[x]), po[x]);
                    po[8 + x] = fmaf(eB, bf2f(vB1[x]), po[8 + x]);
                }
            }
        }
        // merge streams in-register; write P tile
        u16x8 w0, w1;
        #pragma unroll
        for (int x = 0; x < 8; x++) {
            w0[x] = f2bf(pe[x] + po[x]);
            w1[x] = f2bf(pe[8 + x] + po[8 + x]);
        }
        *((u16x8*)&pl[wave][sg][ll * 16])     = w0;
        *((u16x8*)&pl[wave][sg][ll * 16 + 8]) = w1;
        ddsum += dde + ddo;
        asm volatile("s_waitcnt lgkmcnt(0)" ::: "memory");

        // ---- U += P @ M_r ----
        const unsigned short* Mr = Mt + ((size_t)r << 12);
        const bf16x8 pa0 = *((const bf16x8*)&pl[wave][m][quad * 8]);
        const bf16x8 pa1 = *((const bf16x8*)&pl[wave][m][32 + quad * 8]);
        u0 = __builtin_amdgcn_mfma_f32_16x16x32_bf16(pa0, ldb16(Mr + (( 0 + m) << 6)      + quad * 8), u0, 0, 0, 0);
        u1 = __builtin_amdgcn_mfma_f32_16x16x32_bf16(pa0, ldb16(Mr + ((16 + m) << 6)      + quad * 8), u1, 0, 0, 0);
        u2 = __builtin_amdgcn_mfma_f32_16x16x32_bf16(pa0, ldb16(Mr + ((32 + m) << 6)      + quad * 8), u2, 0, 0, 0);
        u3 = __builtin_amdgcn_mfma_f32_16x16x32_bf16(pa0, ldb16(Mr + ((48 + m) << 6)      + quad * 8), u3, 0, 0, 0);
        u0 = __builtin_amdgcn_mfma_f32_16x16x32_bf16(pa1, ldb16(Mr + (( 0 + m) << 6) + 32 + quad * 8), u0, 0, 0, 0);
        u1 = __builtin_amdgcn_mfma_f32_16x16x32_bf16(pa1, ldb16(Mr + ((16 + m) << 6) + 32 + quad * 8), u1, 0, 0, 0);
        u2 = __builtin_amdgcn_mfma_f32_16x16x32_bf16(pa1, ldb16(Mr + ((32 + m) << 6) + 32 + quad * 8), u2, 0, 0, 0);
        u3 = __builtin_amdgcn_mfma_f32_16x16x32_bf16(pa1, ldb16(Mr + ((48 + m) << 6) + 32 + quad * 8), u3, 0, 0, 0);
        asm volatile("s_waitcnt lgkmcnt(0)" ::: "memory");
    }

    // ---- epilogue: agg[n] = U[n] / D[n] ----
    #pragma unroll
    for (int reg = 0; reg < 4; reg++) {
        const int n = n0 + quad * 4 + reg;
        if (n >= N) continue;
        const float dv  = __shfl(ddsum, (quad * 4 + reg) << 2, 64);
        const float inv = (dv == 0.f) ? 0.f : 1.f / dv;
        float* rowp = agg + ((size_t)n << 6) + m;
        rowp[ 0] = u0[reg] * inv;
        rowp[16] = u1[reg] * inv;
        rowp[32] = u2[reg] * inv;
        rowp[48] = u3[reg] * inv;
    }
}

// ------- typed output GEMM (kept f32 for final precision) -------
__global__ void out_typed(const float* __restrict__ agg, const int* __restrict__ ntype,
                          const int* __restrict__ order, const int* __restrict__ tm,
                          const float* __restrict__ Wa, const float* __restrict__ skip,
                          float* __restrict__ out, int N) {
    __shared__ float xs[64][68];
    __shared__ float wsm[64][64];
    int t  = threadIdx.x;
    int n0 = blockIdx.x * 64;
    if (n0 >= tm[12]) return;
    int first = order[n0];
    if (first < 0) return;
    int ty = ntype[first];
    float sg = 1.f / (1.f + expf(-skip[ty]));

    const float4* wg = (const float4*)(Wa + (size_t)ty * DIM * DIM);
    float4* wl = (float4*)&wsm[0][0];
    #pragma unroll
    for (int i = 0; i < 4; i++) {
        float4 w = wg[t + 256 * i];
        w.x *= sg; w.y *= sg; w.z *= sg; w.w *= sg;
        wl[t + 256 * i] = w;
    }
    #pragma unroll
    for (int i = 0; i < 4; i++) {
        int idx = t + 256 * i;
        int row = idx >> 4, c4 = idx & 15;
        int gn = order[n0 + row];
        float4 xv = make_float4(0.f, 0.f, 0.f, 0.f);
        if (gn >= 0) xv = ((const float4*)(agg + (size_t)gn * DIM))[c4];
        ((float4*)&xs[row][0])[c4] = xv;
    }
    __syncthreads();

    int og  = t & 15;
    int ng4 = (t >> 4) * 4;
    float4 a0 = make_float4(0.f,0.f,0.f,0.f), a1 = a0, a2 = a0, a3 = a0;
    #pragma unroll 8
    for (int d = 0; d < DIM; d++) {
        float4 wv = ((const float4*)&wsm[d][0])[og];
        float x0 = xs[ng4 + 0][d];
        float x1 = xs[ng4 + 1][d];
        float x2 = xs[ng4 + 2][d];
        float x3 = xs[ng4 + 3][d];
        a0.x = fmaf(x0, wv.x, a0.x); a0.y = fmaf(x0, wv.y, a0.y);
        a0.z = fmaf(x0, wv.z, a0.z); a0.w = fmaf(x0, wv.w, a0.w);
        a1.x = fmaf(x1, wv.x, a1.x); a1.y = fmaf(x1, wv.y, a1.y);
        a1.z = fmaf(x1, wv.z, a1.z); a1.w = fmaf(x1, wv.w, a1.w);
        a2.x = fmaf(x2, wv.x, a2.x); a2.y = fmaf(x2, wv.y, a2.y);
        a2.z = fmaf(x2, wv.z, a2.z); a2.w = fmaf(x2, wv.w, a2.w);
        a3.x = fmaf(x3, wv.x, a3.x); a3.y = fmaf(x3, wv.y, a3.y);
        a3.z = fmaf(x3, wv.z, a3.z); a3.w = fmaf(x3, wv.w, a3.w);
    }
    int g0 = order[n0 + ng4 + 0];
    int g1 = order[n0 + ng4 + 1];
    int g2 = order[n0 + ng4 + 2];
    int g3 = order[n0 + ng4 + 3];
    if (g0 >= 0) ((float4*)(out + (size_t)g0 * DIM))[og] = a0;
    if (g1 >= 0) ((float4*)(out + (size_t)g1 * DIM))[og] = a1;
    if (g2 >= 0) ((float4*)(out + (size_t)g2 * DIM))[og] = a2;
    if (g3 >= 0) ((float4*)(out + (size_t)g3 * DIM))[og] = a3;
}

extern "C" void kernel_launch(void* const* d_in, const int* in_sizes, int n_in,
                              void* d_out, int out_size, void* d_ws, size_t ws_size,
                              hipStream_t stream) {
    const float* h       = (const float*)d_in[0];
    const int*   ntype   = (const int*)  d_in[1];
    const int*   src     = (const int*)  d_in[2];
    const int*   dst     = (const int*)  d_in[3];
    const int*   et      = (const int*)  d_in[4];
    const float* k_lin   = (const float*)d_in[5];
    const float* q_lin   = (const float*)d_in[6];
    const float* v_lin   = (const float*)d_in[7];
    const float* a_lin   = (const float*)d_in[8];
    const float* rel_att = (const float*)d_in[9];
    const float* rel_msg = (const float*)d_in[10];
    const float* rel_pri = (const float*)d_in[11];
    const float* skip    = (const float*)d_in[12];

    int N = in_sizes[1];
    int E = in_sizes[2];
    int M = N * NR;
    int ocap = N + NT * 64;

    float* ws = (float*)d_ws;
    size_t o = 0;
    unsigned short* kvbf = (unsigned short*)(ws + o); o += (size_t)N * DIM;      // kv[n][128] bf16
    unsigned short* qbf  = (unsigned short*)(ws + o); o += (size_t)N * DIM / 2;
    float* agg  = ws + o; o += (size_t)N * DIM;
    int* off8   = (int*)(ws + o); o += (size_t)M + 1024;   // slack for hoisted loads
    int* cnt8   = (int*)(ws + o); o += (size_t)M;
    int* cnt28  = (int*)(ws + o); o += (size_t)M;          // contiguous with cnt8
    int* se     = (int*)(ws + o); o += (size_t)E;
    int* bsum   = (int*)(ws + o); o += 1024;
    int* order  = (int*)(ws + o); o += (size_t)ocap;
    int* tm     = (int*)(ws + o); o += 16;
    unsigned short* At  = (unsigned short*)(ws + o); o += (size_t)NR * DIM * DIM / 2;
    unsigned short* Mt  = (unsigned short*)(ws + o); o += (size_t)NR * DIM * DIM / 2;
    unsigned short* Wkt = (unsigned short*)(ws + o); o += (size_t)NT * DIM * DIM / 2;
    unsigned short* Wqt = (unsigned short*)(ws + o); o += (size_t)NT * DIM * DIM / 2;
    unsigned short* Wvt = (unsigned short*)(ws + o); o += (size_t)NT * DIM * DIM / 2;

    float* out = (float*)d_out;

    // ---- zero-init via memset (capture-legal) ----
    hipMemsetAsync(order, 0xFF, (size_t)ocap * 4, stream);      // -1 fill
    hipMemsetAsync(tm, 0, 16 * 4, stream);
    hipMemsetAsync(cnt8, 0, (size_t)2 * M * 4, stream);         // cnt8 + cnt28

    // ---- type sort ----
    type_count<<<(N + 255) / 256, 256, 0, stream>>>(ntype, tm, N);
    type_scan<<<1, 64, 0, stream>>>(tm);
    type_scatter<<<(N + 255) / 256, 256, 0, stream>>>(ntype, tm, order, N);

    // ---- all weight transposes+casts (bf16, [mat][n][k]) ----
    prep_all<<<(28 * DIM * DIM + 255) / 256, 256, 0, stream>>>(
        rel_att, rel_msg, k_lin, q_lin, v_lin, At, Mt, Wkt, Wqt, Wvt);

    // ---- typed K/Q/V projections via MFMA ----
    int gridT = (N + NT * 64 + 63) / 64;
    proj_mfma<<<gridT, 256, 0, stream>>>(h, ntype, order, tm, Wkt, Wqt, Wvt,
                                         kvbf, qbf, N);

    // ---- CSR build over (dst, etype) buckets ----
    hist8<<<(E + 255) / 256, 256, 0, stream>>>(dst, et, cnt8, E);
    int nb = (M + 1023) / 1024;
    scan1<<<nb, 1024, 0, stream>>>(cnt8, off8, bsum, M);
    scan2<<<1, 1024, 0, stream>>>(bsum, nb);
    scan3<<<nb, 1024, 0, stream>>>(off8, bsum, M, E);
    scatter8<<<(E + 255) / 256, 256, 0, stream>>>(src, dst, et, off8, cnt28, se, E);

    // ---- fused edge phase ----
    int nb64 = (N + 63) / 64;
    fused_edge<<<nb64, 256, 0, stream>>>(qbf, kvbf, At, Mt, se, off8,
                                         rel_pri, agg, N);

    // ---- typed output GEMM ----
    out_typed<<<gridT, 256, 0, stream>>>(agg, ntype, order, tm, a_lin, skip, out, N);
}